// Round 3
// baseline (1766.282 us; speedup 1.0000x reference)
//
#include <hip/hip_runtime.h>

#define DIM 64
#define XS_STRIDE 192
#define BN_EPS 1e-5f

// ---------------- y = h @ w1  (projection before scatter) ----------------
template<int DIN>
__global__ __launch_bounds__(256) void proj_kernel(
    const float* __restrict__ h, int h_stride, int h_off,
    const float* __restrict__ w1,
    float* __restrict__ y, int N)
{
    constexpr int R = 32;
    __shared__ float w1s[DIN * DIM];     // 32KB (DIN=128) or 16KB
    __shared__ float hin[R][DIN];        // 16KB or 8KB
    const int tid = threadIdx.x;
    const int row0 = blockIdx.x * R;

    for (int i = tid; i < DIN * DIM; i += 256) w1s[i] = w1[i];
    for (int i = tid; i < R * DIN; i += 256) {
        int r = i / DIN, k = i % DIN;    // DIN pow2 -> shifts
        int row = row0 + r;
        hin[r][k] = (row < N) ? h[(size_t)row * h_stride + h_off + k] : 0.f;
    }
    __syncthreads();

    const int c  = tid & 63;
    const int rg = tid >> 6;
    for (int r = rg; r < R; r += 4) {
        int row = row0 + r;
        if (row >= N) break;
        float acc = 0.f;
        #pragma unroll 8
        for (int k = 0; k < DIN; k++) acc += hin[r][k] * w1s[k * DIM + c];
        y[(size_t)row * DIM + c] = acc;
    }
}

// ---------------- z = y + b1 (into xs columns); zero stats ----------------
__global__ void initz_kernel(const float* __restrict__ y, const float* __restrict__ b1,
                             float* __restrict__ xs, int xs_off, int N,
                             float* __restrict__ stats)
{
    int gid = blockIdx.x * blockDim.x + threadIdx.x;
    if (gid < 2 * DIM) stats[gid] = 0.f;
    if (gid >= N * DIM) return;
    int n = gid >> 6, c = gid & 63;
    xs[(size_t)n * XS_STRIDE + xs_off + c] = y[gid] + b1[c];
}

// ---------------- scatter: z[dst] += y[src], 64-wide rows ----------------
__global__ __launch_bounds__(256) void scatter_kernel(
    const float* __restrict__ y, const int* __restrict__ edges, long long E,
    float* __restrict__ xs, int xs_off)
{
    long long gid = (long long)blockIdx.x * 256 + threadIdx.x;
    if (gid >= (E << 6)) return;
    long long e = gid >> 6;
    int f = (int)(gid & 63);
    int src = edges[e];          // int32: harness casts integer inputs to int
    int dst = edges[E + e];
    atomicAdd(&xs[(size_t)dst * XS_STRIDE + xs_off + f], y[(size_t)src * DIM + f]);
}

// ---------------- relu(z) @ w2 + b2, relu, in-place, + stats ----------------
__global__ __launch_bounds__(256) void mlp2_kernel(
    float* __restrict__ xs, int xs_off,
    const float* __restrict__ w2, const float* __restrict__ b2,
    float* __restrict__ stats, int N)
{
    constexpr int R = 32;
    __shared__ float w2s[DIM * DIM];     // 16KB
    __shared__ float zin[R][DIM];        // 8KB
    __shared__ float sred[2][DIM];
    const int tid = threadIdx.x;
    const int row0 = blockIdx.x * R;

    for (int i = tid; i < DIM * DIM; i += 256) w2s[i] = w2[i];
    if (tid < DIM) { sred[0][tid] = 0.f; sred[1][tid] = 0.f; }
    for (int i = tid; i < R * DIM; i += 256) {
        int r = i >> 6, c = i & 63;
        int row = row0 + r;
        zin[r][c] = (row < N) ? fmaxf(xs[(size_t)row * XS_STRIDE + xs_off + c], 0.f) : 0.f;
    }
    __syncthreads();

    const int c  = tid & 63;
    const int rg = tid >> 6;
    float s1 = 0.f, s2 = 0.f;
    for (int r = rg; r < R; r += 4) {
        int row = row0 + r;
        if (row >= N) continue;
        float acc = b2[c];
        #pragma unroll 8
        for (int j = 0; j < DIM; j++) acc += zin[r][j] * w2s[j * DIM + c];
        float v = fmaxf(acc, 0.f);       // F.relu after conv
        xs[(size_t)row * XS_STRIDE + xs_off + c] = v;
        s1 += v; s2 += v * v;
    }
    atomicAdd(&sred[0][c], s1);
    atomicAdd(&sred[1][c], s2);
    __syncthreads();
    if (tid < DIM) {
        atomicAdd(&stats[tid], sred[0][tid]);
        atomicAdd(&stats[DIM + tid], sred[1][tid]);
    }
}

// ---------------- BN params: scale/shift from sum/sumsq ----------------
__global__ void bnparam_kernel(const float* __restrict__ stats,
                               const float* __restrict__ gamma, const float* __restrict__ beta,
                               float* __restrict__ sc, int N) {
    int c = threadIdx.x;  // 64 threads
    float inv_n = 1.0f / (float)N;
    float mean = stats[c] * inv_n;
    float var  = stats[DIM + c] * inv_n - mean * mean;
    float scale = gamma[c] * rsqrtf(var + BN_EPS);
    sc[c] = scale;
    sc[DIM + c] = beta[c] - mean * scale;
}

// ---------------- in-place BN normalize of xs columns ----------------
__global__ void norm_kernel(float* __restrict__ xs, const float* __restrict__ sc,
                            int xs_off, int N) {
    int gid = blockIdx.x * blockDim.x + threadIdx.x;
    if (gid >= N * DIM) return;
    int n = gid >> 6, c = gid & 63;
    size_t p = (size_t)n * XS_STRIDE + xs_off + c;
    xs[p] = xs[p] * sc[c] + sc[DIM + c];
}

// ---------------- per-graph pooling (batch sorted -> binary search) ----------------
__global__ void pool_kernel(const float* __restrict__ xs, const int* __restrict__ batch,
                            float* __restrict__ pool, int N) {
    int g = blockIdx.x;
    int tid = threadIdx.x;  // 192 threads
    int lo = 0, hi = N;
    while (lo < hi) { int mid = (lo + hi) >> 1; if (batch[mid] < g) lo = mid + 1; else hi = mid; }
    int start = lo;
    hi = N;
    while (lo < hi) { int mid = (lo + hi) >> 1; if (batch[mid] < g + 1) lo = mid + 1; else hi = mid; }
    int end = lo;
    float s = 0.f;
    for (int n = start; n < end; n++) s += xs[(size_t)n * XS_STRIDE + tid];
    pool[(size_t)g * XS_STRIDE + tid] = s;
}

extern "C" void kernel_launch(void* const* d_in, const int* in_sizes, int n_in,
                              void* d_out, int out_size, void* d_ws, size_t ws_size,
                              hipStream_t stream) {
    const float* x     = (const float*)d_in[0];
    const int*   edges = (const int*)d_in[1];   // int32 (harness converts integer inputs)
    const int*   batch = (const int*)d_in[2];   // int32

    const int  N    = in_sizes[2];
    const long long E = in_sizes[1] / 2;
    const int  F_IN = in_sizes[0] / N;              // 128
    const int  G    = out_size / XS_STRIDE - N;     // 1000

    const float* W[3][6];
    for (int l = 0; l < 3; l++)
        for (int p = 0; p < 6; p++)
            W[l][p] = (const float*)d_in[4 + l * 6 + p];

    float* out_pool = (float*)d_out;                        // G x 192
    float* out_xs   = out_pool + (size_t)G * XS_STRIDE;     // N x 192

    float* y     = (float*)d_ws;                 // N x 64  (25.6 MB)
    float* stats = y + (size_t)N * DIM;          // 256 floats: sum, sumsq, scale, shift

    const int mblocks = (N + 31) / 32;
    const int eblocks = (N * DIM + 255) / 256;
    const int sblocks = (int)((E * DIM + 255) / 256);

    for (int l = 0; l < 3; l++) {
        const float* h     = (l == 0) ? x : out_xs;
        const int h_stride = (l == 0) ? F_IN : XS_STRIDE;
        const int h_off    = (l == 0) ? 0 : (l - 1) * DIM;

        if (l == 0)
            proj_kernel<128><<<mblocks, 256, 0, stream>>>(h, h_stride, h_off, W[l][0], y, N);
        else
            proj_kernel<64><<<mblocks, 256, 0, stream>>>(h, h_stride, h_off, W[l][0], y, N);

        initz_kernel<<<eblocks, 256, 0, stream>>>(y, W[l][1], out_xs, l * DIM, N, stats);

        scatter_kernel<<<sblocks, 256, 0, stream>>>(y, edges, E, out_xs, l * DIM);

        mlp2_kernel<<<mblocks, 256, 0, stream>>>(out_xs, l * DIM, W[l][2], W[l][3], stats, N);

        bnparam_kernel<<<1, 64, 0, stream>>>(stats, W[l][4], W[l][5], stats + 2 * DIM, N);

        norm_kernel<<<eblocks, 256, 0, stream>>>(out_xs, stats + 2 * DIM, l * DIM, N);
    }

    pool_kernel<<<G, XS_STRIDE, 0, stream>>>(out_xs, batch, out_pool, N);
}

// Round 4
// 1062.803 us; speedup vs baseline: 1.6619x; 1.6619x over previous
//
#include <hip/hip_runtime.h>

#define DIM 64
#define XS_STRIDE 192
#define BN_EPS 1e-5f
#define SCAN_CHUNK 1024

// ---------------- setup: zero counts, cursor, stats ----------------
__global__ void setup_kernel(int* __restrict__ counts, int* __restrict__ cursor, int N,
                             float* __restrict__ stats) {
    int gid = blockIdx.x * blockDim.x + threadIdx.x;
    int stride = gridDim.x * blockDim.x;
    for (int i = gid; i < N; i += stride) { counts[i] = 0; cursor[i] = 0; }
    if (gid < 3 * 256) stats[gid] = 0.f;
}

// ---------------- histogram of dst ----------------
__global__ void hist_kernel(const int* __restrict__ edges, long long E, int* __restrict__ counts) {
    long long e = (long long)blockIdx.x * 256 + threadIdx.x;
    if (e >= E) return;
    atomicAdd(&counts[edges[E + e]], 1);
}

// ---------------- scan step 1: per-chunk sums ----------------
__global__ void scan1_kernel(const int* __restrict__ counts, int N, int* __restrict__ partials) {
    __shared__ int red[256];
    int b = blockIdx.x, t = threadIdx.x;
    int base = b * SCAN_CHUNK;
    int s = 0;
    for (int i = t; i < SCAN_CHUNK; i += 256) {
        int idx = base + i;
        s += (idx < N) ? counts[idx] : 0;
    }
    red[t] = s; __syncthreads();
    for (int o = 128; o > 0; o >>= 1) { if (t < o) red[t] += red[t + o]; __syncthreads(); }
    if (t == 0) partials[b] = red[0];
}

// ---------------- scan step 2: exclusive scan of partials (tiny) ----------------
__global__ void scan2_kernel(int* __restrict__ partials, int nb, int* __restrict__ offsets_end) {
    if (threadIdx.x == 0) {
        int acc = 0;
        for (int i = 0; i < nb; i++) { int v = partials[i]; partials[i] = acc; acc += v; }
        *offsets_end = acc;   // offsets[N] = E
    }
}

// ---------------- scan step 3: chunk-local exclusive scan -> offsets ----------------
__global__ void scan3_kernel(const int* __restrict__ counts, int N,
                             const int* __restrict__ partials, int* __restrict__ offsets) {
    __shared__ int sbuf[2][256];
    int b = blockIdx.x, t = threadIdx.x;
    int base = b * SCAN_CHUNK;
    int v[4]; int s = 0;
    #pragma unroll
    for (int j = 0; j < 4; j++) {
        int idx = base + t * 4 + j;
        v[j] = (idx < N) ? counts[idx] : 0;
        s += v[j];
    }
    sbuf[0][t] = s; __syncthreads();
    int cur = 0;
    for (int o = 1; o < 256; o <<= 1) {
        int val = sbuf[cur][t];
        if (t >= o) val += sbuf[cur][t - o];
        sbuf[cur ^ 1][t] = val; __syncthreads(); cur ^= 1;
    }
    int excl = sbuf[cur][t] - s;
    int off = partials[b] + excl;
    #pragma unroll
    for (int j = 0; j < 4; j++) {
        int idx = base + t * 4 + j;
        if (idx < N) offsets[idx] = off;
        off += v[j];
    }
}

// ---------------- fill CSR edge index (src ids bucketed by dst) ----------------
__global__ void fill_kernel(const int* __restrict__ edges, long long E,
                            const int* __restrict__ offsets, int* __restrict__ cursor,
                            int* __restrict__ eidx) {
    long long e = (long long)blockIdx.x * 256 + threadIdx.x;
    if (e >= E) return;
    int src = edges[e];
    int dst = edges[E + e];
    int pos = atomicAdd(&cursor[dst], 1);
    eidx[offsets[dst] + pos] = src;
}

// ---------------- y = h @ w1  (projection before aggregation) ----------------
template<int DIN>
__global__ __launch_bounds__(256) void proj_kernel(
    const float* __restrict__ h, int h_stride, int h_off,
    const float* __restrict__ w1,
    float* __restrict__ y, int N)
{
    constexpr int R = 32;
    __shared__ float w1s[DIN * DIM];
    __shared__ float hin[R][DIN];
    const int tid = threadIdx.x;
    const int row0 = blockIdx.x * R;

    for (int i = tid; i < DIN * DIM; i += 256) w1s[i] = w1[i];
    for (int i = tid; i < R * DIN; i += 256) {
        int r = i / DIN, k = i % DIN;
        int row = row0 + r;
        hin[r][k] = (row < N) ? h[(size_t)row * h_stride + h_off + k] : 0.f;
    }
    __syncthreads();

    const int c  = tid & 63;
    const int rg = tid >> 6;
    float acc[8];
    #pragma unroll
    for (int i = 0; i < 8; i++) acc[i] = 0.f;
    for (int k = 0; k < DIN; k++) {
        float wv = w1s[k * DIM + c];
        #pragma unroll
        for (int i = 0; i < 8; i++) acc[i] += hin[rg + 4 * i][k] * wv;
    }
    #pragma unroll
    for (int i = 0; i < 8; i++) {
        int row = row0 + rg + 4 * i;
        if (row < N) y[(size_t)row * DIM + c] = acc[i];
    }
}

// ---- fused: z = y[n] + b1 + sum_{j->n} y[j]; relu; @w2+b2; relu; write xs + stats ----
__global__ __launch_bounds__(256) void aggmlp_kernel(
    const float* __restrict__ y,
    const int* __restrict__ offsets, const int* __restrict__ eidx,
    const float* __restrict__ b1,
    const float* __restrict__ w2, const float* __restrict__ b2,
    float* __restrict__ xs, int xs_off,
    float* __restrict__ stats, int N)
{
    constexpr int R = 32;
    __shared__ float w2s[DIM * DIM];     // 16KB
    __shared__ float zin[R][DIM];        // 8KB
    __shared__ float sred[2][DIM];
    const int tid = threadIdx.x;
    const int row0 = blockIdx.x * R;
    const int lane = tid & 63;
    const int wv_  = tid >> 6;

    for (int i = tid; i < DIM * DIM; i += 256) w2s[i] = w2[i];
    if (tid < DIM) { sred[0][tid] = 0.f; sred[1][tid] = 0.f; }

    // aggregation: each wave owns rows wv_, wv_+4, ... (lane = feature)
    for (int r = wv_; r < R; r += 4) {
        int node = row0 + r;
        float acc = 0.f;
        if (node < N) {
            acc = y[(size_t)node * DIM + lane] + b1[lane];
            int p = offsets[node];
            int pe = offsets[node + 1];
            for (; p + 1 < pe; p += 2) {
                int s0 = eidx[p], s1 = eidx[p + 1];
                float v0 = y[(size_t)s0 * DIM + lane];
                float v1 = y[(size_t)s1 * DIM + lane];
                acc += v0; acc += v1;
            }
            if (p < pe) acc += y[(size_t)eidx[p] * DIM + lane];
            acc = fmaxf(acc, 0.f);       // relu between the two linear layers
        }
        zin[r][lane] = acc;
    }
    __syncthreads();

    // GEMM: relu(z) @ w2 + b2, register-tiled (8 rows/thread)
    float acc[8];
    #pragma unroll
    for (int i = 0; i < 8; i++) acc[i] = b2[lane];
    for (int k = 0; k < DIM; k++) {
        float w = w2s[k * DIM + lane];
        #pragma unroll
        for (int i = 0; i < 8; i++) acc[i] += zin[wv_ + 4 * i][k] * w;
    }
    float s1 = 0.f, s2 = 0.f;
    #pragma unroll
    for (int i = 0; i < 8; i++) {
        int row = row0 + wv_ + 4 * i;
        if (row < N) {
            float v = fmaxf(acc[i], 0.f);   // F.relu after conv
            xs[(size_t)row * XS_STRIDE + xs_off + lane] = v;
            s1 += v; s2 += v * v;
        }
    }
    atomicAdd(&sred[0][lane], s1);
    atomicAdd(&sred[1][lane], s2);
    __syncthreads();
    if (tid < DIM) {
        atomicAdd(&stats[tid], sred[0][tid]);
        atomicAdd(&stats[DIM + tid], sred[1][tid]);
    }
}

// ---------------- BN params: scale/shift from sum/sumsq ----------------
__global__ void bnparam_kernel(const float* __restrict__ stats,
                               const float* __restrict__ gamma, const float* __restrict__ beta,
                               float* __restrict__ sc, int N) {
    int c = threadIdx.x;  // 64 threads
    float inv_n = 1.0f / (float)N;
    float mean = stats[c] * inv_n;
    float var  = stats[DIM + c] * inv_n - mean * mean;
    float scale = gamma[c] * rsqrtf(var + BN_EPS);
    sc[c] = scale;
    sc[DIM + c] = beta[c] - mean * scale;
}

// ---------------- in-place BN normalize of xs columns ----------------
__global__ void norm_kernel(float* __restrict__ xs, const float* __restrict__ sc,
                            int xs_off, int N) {
    int gid = blockIdx.x * blockDim.x + threadIdx.x;
    if (gid >= N * DIM) return;
    int n = gid >> 6, c = gid & 63;
    size_t p = (size_t)n * XS_STRIDE + xs_off + c;
    xs[p] = xs[p] * sc[c] + sc[DIM + c];
}

// ---------------- per-graph pooling (batch sorted -> binary search) ----------------
__global__ void pool_kernel(const float* __restrict__ xs, const int* __restrict__ batch,
                            float* __restrict__ pool, int N) {
    int g = blockIdx.x;
    int tid = threadIdx.x;  // 192 threads
    int lo = 0, hi = N;
    while (lo < hi) { int mid = (lo + hi) >> 1; if (batch[mid] < g) lo = mid + 1; else hi = mid; }
    int start = lo;
    hi = N;
    while (lo < hi) { int mid = (lo + hi) >> 1; if (batch[mid] < g + 1) lo = mid + 1; else hi = mid; }
    int end = lo;
    float s = 0.f;
    for (int n = start; n < end; n++) s += xs[(size_t)n * XS_STRIDE + tid];
    pool[(size_t)g * XS_STRIDE + tid] = s;
}

extern "C" void kernel_launch(void* const* d_in, const int* in_sizes, int n_in,
                              void* d_out, int out_size, void* d_ws, size_t ws_size,
                              hipStream_t stream) {
    const float* x     = (const float*)d_in[0];
    const int*   edges = (const int*)d_in[1];   // int32 (harness converts integer inputs)
    const int*   batch = (const int*)d_in[2];   // int32

    const int  N    = in_sizes[2];
    const long long E = in_sizes[1] / 2;
    const int  F_IN = in_sizes[0] / N;              // 128
    const int  G    = out_size / XS_STRIDE - N;     // 1000

    const float* W[3][6];
    for (int l = 0; l < 3; l++)
        for (int p = 0; p < 6; p++)
            W[l][p] = (const float*)d_in[4 + l * 6 + p];

    float* out_pool = (float*)d_out;                        // G x 192
    float* out_xs   = out_pool + (size_t)G * XS_STRIDE;     // N x 192

    // workspace layout (~33 MB)
    float* y       = (float*)d_ws;                      // N x 64 (25.6 MB)
    float* stats   = y + (size_t)N * DIM;               // 3 x 256 floats
    int*   counts  = (int*)(stats + 3 * 256);           // N
    int*   cursor  = counts + N;                        // N
    int*   offsets = cursor + N;                        // N + 1
    int*   partials= offsets + N + 1;                   // ~128
    int*   eidx    = partials + 256;                    // E (6.4 MB)

    const int eblk   = (int)((E + 255) / 256);
    const int nscan  = (N + SCAN_CHUNK - 1) / SCAN_CHUNK;
    const int mblocks = (N + 31) / 32;
    const int nblocks = (N * DIM + 255) / 256;

    // ---- build CSR once (shared by all 3 layers) ----
    setup_kernel<<<512, 256, 0, stream>>>(counts, cursor, N, stats);
    hist_kernel<<<eblk, 256, 0, stream>>>(edges, E, counts);
    scan1_kernel<<<nscan, 256, 0, stream>>>(counts, N, partials);
    scan2_kernel<<<1, 64, 0, stream>>>(partials, nscan, offsets + N);
    scan3_kernel<<<nscan, 256, 0, stream>>>(counts, N, partials, offsets);
    fill_kernel<<<eblk, 256, 0, stream>>>(edges, E, offsets, cursor, eidx);

    for (int l = 0; l < 3; l++) {
        const float* h     = (l == 0) ? x : out_xs;
        const int h_stride = (l == 0) ? F_IN : XS_STRIDE;
        const int h_off    = (l == 0) ? 0 : (l - 1) * DIM;
        float* statsL = stats + l * 256;

        if (l == 0)
            proj_kernel<128><<<mblocks, 256, 0, stream>>>(h, h_stride, h_off, W[l][0], y, N);
        else
            proj_kernel<64><<<mblocks, 256, 0, stream>>>(h, h_stride, h_off, W[l][0], y, N);

        aggmlp_kernel<<<mblocks, 256, 0, stream>>>(y, offsets, eidx,
            W[l][1], W[l][2], W[l][3], out_xs, l * DIM, statsL, N);

        bnparam_kernel<<<1, 64, 0, stream>>>(statsL, W[l][4], W[l][5], statsL + 2 * DIM, N);

        norm_kernel<<<nblocks, 256, 0, stream>>>(out_xs, statsL + 2 * DIM, l * DIM, N);
    }

    pool_kernel<<<G, XS_STRIDE, 0, stream>>>(out_xs, batch, out_pool, N);
}